// Round 9
// baseline (528.657 us; speedup 1.0000x reference)
//
#include <hip/hip_runtime.h>

#define HH 512
#define WW 512
#define HW 262144          // 512*512
#define NPIX 1048576       // 4*512*512
#define NPIXF 1048576.0f

typedef float f4 __attribute__((ext_vector_type(4)));

__device__ __forceinline__ float leaky(float v) { return v > 0.f ? v : 0.01f * v; }

// replication count of source index i at level size s (nearest upsample to 512)
__device__ __forceinline__ float repw(int i, int s) {
    return (float)(((i + 1) * 512 + s - 1) / s - (i * 512 + s - 1) / s);
}

__device__ __forceinline__ void hins(unsigned long long& h0, unsigned long long& h1,
                                     unsigned& c16, int val) {
    unsigned long long inc = 1ull << ((val & 7) * 8);
    h0 += (val < 8) ? inc : 0;
    h1 += (val >= 8 && val < 16) ? inc : 0;
    c16 += (unsigned)(val >> 4);
}
__device__ __forceinline__ void hrem(unsigned long long& h0, unsigned long long& h1,
                                     unsigned& c16, int val) {
    unsigned long long inc = 1ull << ((val & 7) * 8);
    h0 -= (val < 8) ? inc : 0;
    h1 -= (val >= 8 && val < 16) ? inc : 0;
    c16 -= (unsigned)(val >> 4);
}

// ---------------------------------------------------------------------------
// Mode pooling v3 (round-5 proven, 469.6us config): 768 blocks, 16 rows x 256
// cols, double-buffered colhist mirror, one __syncthreads per row.
// ---------------------------------------------------------------------------
__global__ __launch_bounds__(256) void mode_kernel(const float* __restrict__ x,
                                                   unsigned char* __restrict__ modeq) {
    __shared__ unsigned char q[26 * 272];
    __shared__ unsigned ch[2][267 * 5];
    const int plane = blockIdx.z;
    const int tc0 = blockIdx.x * 256;
    const int tr0 = blockIdx.y * 16;
    const float* xp = x + (size_t)plane * HW;
    for (int idx = threadIdx.x; idx < 26 * 266; idx += 256) {
        int r = idx / 266;
        int cc = idx - r * 266;
        int gr = tr0 + r - 5; gr = gr < 0 ? -gr : (gr > 511 ? 1022 - gr : gr);
        int gc = tc0 + cc - 5; gc = gc < 0 ? -gc : (gc > 511 ? 1022 - gc : gc);
        float v = rintf(xp[gr * WW + gc] * 15.9375f);   // 255/16, round-half-even
        v = fminf(fmaxf(v, 0.f), 16.f);
        q[r * 272 + cc] = (unsigned char)(int)v;
    }
    const int t = threadIdx.x;
    unsigned long long A0 = 0, A1 = 0; unsigned A2 = 0;
    unsigned long long B0 = 0, B1 = 0; unsigned B2 = 0;
    __syncthreads();
    for (int r = 0; r < 16; ++r) {
        if (r == 0) {
            #pragma unroll
            for (int v = 0; v < 11; ++v) {
                hins(A0, A1, A2, q[v * 272 + t]);
                if (t < 10) hins(B0, B1, B2, q[v * 272 + 256 + t]);
            }
        } else {
            hrem(A0, A1, A2, q[(r - 1) * 272 + t]);
            hins(A0, A1, A2, q[(r + 10) * 272 + t]);
            if (t < 10) {
                hrem(B0, B1, B2, q[(r - 1) * 272 + 256 + t]);
                hins(B0, B1, B2, q[(r + 10) * 272 + 256 + t]);
            }
        }
        unsigned* cb = ch[r & 1];
        cb[t * 5 + 0] = (unsigned)A0;
        cb[t * 5 + 1] = (unsigned)(A0 >> 32);
        cb[t * 5 + 2] = (unsigned)A1;
        cb[t * 5 + 3] = (unsigned)(A1 >> 32);
        cb[t * 5 + 4] = A2;
        if (t < 10) {
            cb[(256 + t) * 5 + 0] = (unsigned)B0;
            cb[(256 + t) * 5 + 1] = (unsigned)(B0 >> 32);
            cb[(256 + t) * 5 + 2] = (unsigned)B1;
            cb[(256 + t) * 5 + 3] = (unsigned)(B1 >> 32);
            cb[(256 + t) * 5 + 4] = B2;
        }
        __syncthreads();
        unsigned long long H0 = 0, H1 = 0; unsigned C = 0;
        #pragma unroll
        for (int v = 0; v < 11; ++v) {
            const unsigned* p = &cb[(t + v) * 5];
            H0 += (unsigned long long)p[0] | ((unsigned long long)p[1] << 32);
            H1 += (unsigned long long)p[2] | ((unsigned long long)p[3] << 32);
            C += p[4];
        }
        unsigned m = 0;
        #pragma unroll
        for (int i = 0; i < 8; ++i) {
            unsigned cnt = (unsigned)(H0 >> (8 * i)) & 0xFFu;
            unsigned val = (cnt << 8) | (unsigned)(16 - i);
            m = m > val ? m : val;
        }
        #pragma unroll
        for (int i = 8; i < 16; ++i) {
            unsigned cnt = (unsigned)(H1 >> (8 * (i - 8))) & 0xFFu;
            unsigned val = (cnt << 8) | (unsigned)(16 - i);
            m = m > val ? m : val;
        }
        unsigned val16 = (C << 8);
        m = m > val16 ? m : val16;
        int k = 16 - (int)(m & 0xFFu);
        modeq[(size_t)plane * HW + (size_t)(tr0 + r) * WW + tc0 + t] = (unsigned char)k;
    }
}

// ---------------------------------------------------------------------------
// Joint histogram only. 128 blocks, coalesced partial[blk*4913+bin] writes.
// ---------------------------------------------------------------------------
__global__ __launch_bounds__(256) void hist_kernel(const unsigned char* __restrict__ modeq,
                                                   unsigned* __restrict__ partial) {
    __shared__ unsigned lh[4913];
    for (int i = threadIdx.x; i < 4913; i += 256) lh[i] = 0;
    __syncthreads();
    int base = blockIdx.x * 8192;
    int b = base >> 18;
    int hw0 = base & (HW - 1);
    const unsigned char* mp = modeq + (size_t)b * 3 * HW;
    #pragma unroll
    for (int j = 0; j < 8; ++j) {
        int g = threadIdx.x + 256 * j;
        int hw = hw0 + g * 4;
        unsigned u0 = *(const unsigned*)(mp + hw);
        unsigned u1 = *(const unsigned*)(mp + hw + HW);
        unsigned u2 = *(const unsigned*)(mp + hw + 2 * HW);
        #pragma unroll
        for (int k = 0; k < 4; ++k) {
            int k0 = (u0 >> (8 * k)) & 0xFF;
            int k1 = (u1 >> (8 * k)) & 0xFF;
            int k2 = (u2 >> (8 * k)) & 0xFF;
            atomicAdd(&lh[k0 + 17 * k1 + 289 * k2], 1u);
        }
    }
    __syncthreads();
    unsigned* pp = partial + blockIdx.x * 4913;
    for (int i = threadIdx.x; i < 4913; i += 256) pp[i] = lh[i];
}

// ---------------------------------------------------------------------------
// solveBF (round-8 coalesced version — the sound piece of that round):
// (0) coalesced 128-way reduce of partial into LDS histf; (A) t1 moments;
// (B) BN1 closed form -> p1 (block 0 publishes); (C) bin sweep -> tpart.
// ---------------------------------------------------------------------------
__global__ __launch_bounds__(256) void solveBF_kernel(const unsigned* __restrict__ partial,
                                                      const float* __restrict__ w1,
                                                      const float* __restrict__ b1,
                                                      const float* __restrict__ w2,
                                                      const float* __restrict__ b2,
                                                      const float* __restrict__ g1,
                                                      const float* __restrict__ bb1,
                                                      float* __restrict__ p1g,
                                                      float* __restrict__ tpart) {
    __shared__ float histf[4913];
    __shared__ float mred[27][4];
    __shared__ float mom[27];
    __shared__ float a1s[32], c1s[32];
    __shared__ float rs[8][32], rq[8][32];
    const int t = threadIdx.x;
    const int c = t & 31;
    const int sub = t >> 5;
    for (int bin = t; bin < 4913; bin += 256) {
        unsigned s = 0;
        for (int blk = 0; blk < 128; ++blk) s += partial[blk * 4913 + bin];
        histf[bin] = (float)s;
    }
    float w1r[18], b1r[6];
    #pragma unroll
    for (int k = 0; k < 18; ++k) w1r[k] = w1[k];
    #pragma unroll
    for (int o = 0; o < 6; ++o) b1r[o] = b1[o];
    __syncthreads();
    float M[27];
    #pragma unroll
    for (int i = 0; i < 27; ++i) M[i] = 0.f;
    for (int bin = t; bin < 4913; bin += 256) {
        float cnt = histf[bin];
        int k0 = bin % 17;
        int r = bin / 17;
        int k1 = r % 17;
        int k2 = r / 17;
        float xm0 = k0 * 0.0625f, xm1 = k1 * 0.0625f, xm2 = k2 * 0.0625f;
        float t1[6];
        #pragma unroll
        for (int o = 0; o < 6; ++o)
            t1[o] = leaky(xm0 * w1r[o * 3] + xm1 * w1r[o * 3 + 1] + xm2 * w1r[o * 3 + 2] + b1r[o]);
        #pragma unroll
        for (int o = 0; o < 6; ++o) M[o] += cnt * t1[o];
        int ii = 6;
        #pragma unroll
        for (int j = 0; j < 6; ++j)
            #pragma unroll
            for (int k = j; k < 6; ++k) { M[ii] += cnt * t1[j] * t1[k]; ++ii; }
    }
    int wv = t >> 6;
    #pragma unroll
    for (int i = 0; i < 27; ++i) {
        float v = M[i];
        #pragma unroll
        for (int off = 32; off >= 1; off >>= 1) v += __shfl_xor(v, off);
        if ((t & 63) == 0) mred[i][wv] = v;
    }
    __syncthreads();
    if (t < 27) mom[t] = mred[t][0] + mred[t][1] + mred[t][2] + mred[t][3];
    __syncthreads();
    if (t < 32) {
        float w2r[6];
        #pragma unroll
        for (int k = 0; k < 6; ++k) w2r[k] = w2[t * 6 + k];
        float b2c = b2[t];
        float wm1 = 0.f;
        #pragma unroll
        for (int k = 0; k < 6; ++k) wm1 += w2r[k] * mom[k];
        float q = 0.f;
        int ii = 6;
        #pragma unroll
        for (int j = 0; j < 6; ++j)
            #pragma unroll
            for (int k = j; k < 6; ++k) {
                float f = w2r[j] * w2r[k] * mom[ii];
                q += (j == k) ? f : 2.f * f;
                ++ii;
            }
        float mean = b2c + wm1 / NPIXF;
        float ex2 = b2c * b2c + 2.f * b2c * (wm1 / NPIXF) + q / NPIXF;
        float var = ex2 - mean * mean;
        float a = g1[t] * rsqrtf(var + 1e-5f);
        a1s[t] = a;
        c1s[t] = bb1[t] - mean * a;
        if (blockIdx.x == 0) { p1g[t] = a; p1g[32 + t] = c1s[t]; }
    }
    __syncthreads();
    float w2r[6];
    #pragma unroll
    for (int k = 0; k < 6; ++k) w2r[k] = w2[c * 6 + k];
    float b2c = b2[c];
    float a1 = a1s[c], c1 = c1s[c];
    float sm = 0.f, sq = 0.f;
    for (int bin = blockIdx.x + 32 * sub; bin < 4913; bin += 256) {
        float cnt = histf[bin];
        int k0 = bin % 17;
        int r = bin / 17;
        int k1 = r % 17;
        int k2 = r / 17;
        float xm0 = k0 * 0.0625f, xm1 = k1 * 0.0625f, xm2 = k2 * 0.0625f;
        float t1[6];
        #pragma unroll
        for (int o = 0; o < 6; ++o)
            t1[o] = leaky(xm0 * w1r[o * 3] + xm1 * w1r[o * 3 + 1] + xm2 * w1r[o * 3 + 2] + b1r[o]);
        float h2 = b2c;
        #pragma unroll
        for (int k = 0; k < 6; ++k) h2 += w2r[k] * t1[k];
        float tt = leaky(a1 * h2 + c1);
        sm += cnt * tt;
        sq += cnt * tt * tt;
    }
    rs[sub][c] = sm; rq[sub][c] = sq;
    __syncthreads();
    if (t < 32) {
        float s = 0.f, qq = 0.f;
        #pragma unroll
        for (int g = 0; g < 8; ++g) { s += rs[g][t]; qq += rq[g][t]; }
        tpart[blockIdx.x * 64 + t] = s;
        tpart[blockIdx.x * 64 + 32 + t] = qq;
    }
}

// Separate fin2 (round-5 proven shape): 1x32, sums tpart, writes p2.
__global__ void fin2_kernel(const float* __restrict__ tpart, const float* __restrict__ w3,
                            const float* __restrict__ b3, const float* __restrict__ g,
                            const float* __restrict__ bb, float* __restrict__ p2) {
    int c = threadIdx.x;
    float s = 0.f, qq = 0.f;
    #pragma unroll
    for (int k = 0; k < 32; ++k) { s += tpart[k * 64 + c]; qq += tpart[k * 64 + 32 + c]; }
    float mt = s / NPIXF;
    float vt = qq / NPIXF - mt * mt;
    float m2 = w3[c] * mt + b3[c];
    float v2 = w3[c] * w3[c] * vt;
    float a = g[c] * rsqrtf(v2 + 1e-5f);
    p2[c] = a;
    p2[32 + c] = bb[c] - m2 * a;
}

// ---------------------------------------------------------------------------
// Level-1 downsample fused with prepare chain (round-5 proven: no stats,
// no preamble — reads p1/p2 from global).
// ---------------------------------------------------------------------------
__global__ __launch_bounds__(64) void d1_kernel(const unsigned char* __restrict__ modeq,
                                                const float* __restrict__ w1,
                                                const float* __restrict__ b1,
                                                const float* __restrict__ w2,
                                                const float* __restrict__ b2,
                                                const float* __restrict__ w3,
                                                const float* __restrict__ b3,
                                                const float* __restrict__ p1,
                                                const float* __restrict__ p2,
                                                const float* __restrict__ kd,
                                                float* __restrict__ d1) {
    int j = blockIdx.x * 64 + threadIdx.x;
    if (j >= 171) return;
    int i = blockIdx.y;
    int b = blockIdx.z;
    float acc[32];
    #pragma unroll
    for (int c = 0; c < 32; ++c) acc[c] = 0.f;
    const unsigned char* mp = modeq + (size_t)b * 3 * HW;
    #pragma unroll
    for (int u = 0; u < 3; ++u) {
        int r = 3 * i - 1 + u;
        if (r < 0 || r > 511) continue;
        #pragma unroll
        for (int v = 0; v < 3; ++v) {
            int col = 3 * j - 1 + v;
            if (col < 0 || col > 511) continue;
            int off = r * WW + col;
            float xm0 = mp[off] * 0.0625f, xm1 = mp[off + HW] * 0.0625f, xm2 = mp[off + 2 * HW] * 0.0625f;
            float t1[6];
            #pragma unroll
            for (int o = 0; o < 6; ++o)
                t1[o] = leaky(xm0 * w1[o * 3] + xm1 * w1[o * 3 + 1] + xm2 * w1[o * 3 + 2] + b1[o]);
            #pragma unroll
            for (int c = 0; c < 32; ++c) {
                float h2 = b2[c];
                #pragma unroll
                for (int k = 0; k < 6; ++k) h2 += w2[c * 6 + k] * t1[k];
                float t = leaky(h2 * p1[c] + p1[32 + c]);
                float uu = t * w3[c] + b3[c];
                float hv = leaky(uu * p2[c] + p2[32 + c]);
                acc[c] += hv * kd[c * 9 + u * 3 + v];
            }
        }
    }
    size_t base = ((size_t)(b * 32) * 171 + i) * 171 + j;
    #pragma unroll
    for (int c = 0; c < 32; ++c) d1[base + (size_t)c * 29241] = acc[c];
}

// ---------------------------------------------------------------------------
// Fused pyramid tail: L1 stats + levels 2..6 + stats, pstats non-atomic.
// ---------------------------------------------------------------------------
__device__ __forceinline__ void red_store(float sm, float sq, float* rsc, float* ps) {
    #pragma unroll
    for (int off = 32; off >= 1; off >>= 1) {
        sm += __shfl_xor(sm, off);
        sq += __shfl_xor(sq, off);
    }
    __syncthreads();
    int wv = threadIdx.x >> 6;
    if ((threadIdx.x & 63) == 0) { rsc[wv] = sm; rsc[8 + wv] = sq; }
    __syncthreads();
    if (threadIdx.x == 0) {
        ps[0] = rsc[0] + rsc[1] + rsc[2] + rsc[3];
        ps[1] = rsc[8] + rsc[9] + rsc[10] + rsc[11];
    }
}

__device__ __forceinline__ void lvl(const float* src, int sin, float* dstL,
                                    float* dstG, int sout, const float* kreg,
                                    float* rsc, float* ps) {
    float sm = 0.f, sq = 0.f;
    int n = sout * sout;
    for (int i = threadIdx.x; i < n; i += 256) {
        int oi = i / sout, oj = i - oi * sout;
        float acc = 0.f;
        #pragma unroll
        for (int u = 0; u < 3; ++u) {
            int r = 3 * oi - 1 + u;
            if ((unsigned)r >= (unsigned)sin) continue;
            #pragma unroll
            for (int v = 0; v < 3; ++v) {
                int cc = 3 * oj - 1 + v;
                if ((unsigned)cc >= (unsigned)sin) continue;
                acc += src[r * sin + cc] * kreg[u * 3 + v];
            }
        }
        dstG[i] = acc;
        if (dstL) dstL[i] = acc;
        float w = repw(oi, sout) * repw(oj, sout);
        sm += w * acc;
        sq += w * acc * acc;
    }
    red_store(sm, sq, rsc, ps);
}

__global__ __launch_bounds__(256) void pyramid_kernel(const float* __restrict__ d1,
                                                      float* __restrict__ d2,
                                                      float* __restrict__ d3,
                                                      float* __restrict__ d4,
                                                      float* __restrict__ d5,
                                                      float* __restrict__ d6,
                                                      const float* __restrict__ kd,
                                                      float* __restrict__ pstats) {
    __shared__ float buf2[3249];
    __shared__ float buf3[361];
    __shared__ float buf4[49];
    __shared__ float buf5[9];
    __shared__ float rsc[16];
    int bc = blockIdx.x;
    int c = bc & 31;
    float kreg[9];
    #pragma unroll
    for (int qq = 0; qq < 9; ++qq) kreg[qq] = kd[c * 9 + qq];
    float* ps = pstats + (size_t)bc * 12;
    const float* s1 = d1 + (size_t)bc * 29241;
    float sm = 0.f, sq = 0.f;
    for (int i = threadIdx.x; i < 29241; i += 256) {
        int oi = i / 171, oj = i - oi * 171;
        float w = repw(oi, 171) * repw(oj, 171);
        float v = s1[i];
        sm += w * v;
        sq += w * v * v;
    }
    red_store(sm, sq, rsc, ps + 0);
    lvl(s1, 171, buf2, d2 + (size_t)bc * 3249, 57, kreg, rsc, ps + 2);
    lvl(buf2, 57, buf3, d3 + (size_t)bc * 361, 19, kreg, rsc, ps + 4);
    lvl(buf3, 19, buf4, d4 + (size_t)bc * 49, 7, kreg, rsc, ps + 6);
    lvl(buf4, 7, buf5, d5 + (size_t)bc * 9, 3, kreg, rsc, ps + 8);
    lvl(buf5, 3, nullptr, d6 + bc, 1, kreg, rsc, ps + 10);
}

// Separate fin3 (round-5 proven shape), reading non-atomic pstats.
__global__ void fin3_kernel(const float* __restrict__ pstats, const float* __restrict__ kw,
                            const float* __restrict__ gw, const float* __restrict__ bw,
                            const float* __restrict__ kh, const float* __restrict__ gh,
                            const float* __restrict__ bh, float* __restrict__ lp) {
    int t = threadIdx.x;
    if (t >= 192) return;
    int l = t >> 5, c = t & 31;
    float sm = 0.f, sq = 0.f;
    #pragma unroll
    for (int b = 0; b < 4; ++b) {
        const float* ps = pstats + (size_t)(b * 32 + c) * 12 + 2 * l;
        sm += ps[0];
        sq += ps[1];
    }
    float mz = sm / NPIXF;
    float vz = sq / NPIXF - mz * mz;
    float kwc = kw[c];
    float aw = gw[c] * rsqrtf(kwc * kwc * vz + 1e-5f);
    float khc = kh[c];
    float ah = gh[c] * rsqrtf(khc * khc * vz + 1e-5f);
    float* o = lp + (size_t)(l * 32 + c) * 4;
    o[0] = kwc * aw;
    o[1] = bw[c] - kwc * mz * aw;
    o[2] = khc * ah;
    o[3] = bh[c] - khc * mz * ah;
}

// Final (round-5 proven): 4 px/thread, nontemporal float4 stores, reads lp.
__global__ __launch_bounds__(256) void final_kernel(const float* __restrict__ d1,
                                                    const float* __restrict__ d2,
                                                    const float* __restrict__ d3,
                                                    const float* __restrict__ d4,
                                                    const float* __restrict__ d5,
                                                    const float* __restrict__ d6,
                                                    const float* __restrict__ lp,
                                                    float* __restrict__ out) {
    int idx = blockIdx.x * 256 + threadIdx.x;
    int w4 = (idx & 127) << 2;
    int h = (idx >> 7) & 511;
    int c = (idx >> 16) & 31;
    int b = idx >> 21;
    const float* ds[6] = {d1, d2, d3, d4, d5, d6};
    const int ss[6] = {171, 57, 19, 7, 3, 1};
    float accw[4] = {0.f, 0.f, 0.f, 0.f};
    float acch[4] = {0.f, 0.f, 0.f, 0.f};
    #pragma unroll
    for (int l = 0; l < 6; ++l) {
        int s = ss[l];
        int sh = (h * s) >> 9;
        const float* base = ds[l] + ((size_t)(b * 32 + c) * s + sh) * s;
        const float* a = lp + (size_t)(l * 32 + c) * 4;
        float a0 = a[0], a1 = a[1], a2 = a[2], a3 = a[3];
        #pragma unroll
        for (int k = 0; k < 4; ++k) {
            int sw = ((w4 + k) * s) >> 9;
            float val = base[sw];
            accw[k] += leaky(val * a0 + a1);
            acch[k] += leaky(val * a2 + a3);
        }
    }
    size_t o = (((size_t)(b * 64 + c)) << 18) + ((size_t)h << 9) + w4;
    f4 vw = {accw[0], accw[1], accw[2], accw[3]};
    f4 vh = {acch[0], acch[1], acch[2], acch[3]};
    __builtin_nontemporal_store(vw, (f4*)(out + o));
    __builtin_nontemporal_store(vh, (f4*)(out + o + (((size_t)32) << 18)));
}

extern "C" void kernel_launch(void* const* d_in, const int* in_sizes, int n_in,
                              void* d_out, int out_size, void* d_ws, size_t ws_size,
                              hipStream_t stream) {
    const float* x     = (const float*)d_in[0];
    const float* w1    = (const float*)d_in[1];
    const float* b1    = (const float*)d_in[2];
    const float* w2    = (const float*)d_in[3];
    const float* b2    = (const float*)d_in[4];
    const float* bn1g  = (const float*)d_in[5];
    const float* bn1b  = (const float*)d_in[6];
    const float* w3    = (const float*)d_in[7];
    const float* b3    = (const float*)d_in[8];
    const float* bn2g  = (const float*)d_in[9];
    const float* bn2b  = (const float*)d_in[10];
    const float* kd    = (const float*)d_in[11];
    const float* kw    = (const float*)d_in[12];
    const float* bnwg  = (const float*)d_in[13];
    const float* bnwb  = (const float*)d_in[14];
    const float* kh    = (const float*)d_in[15];
    const float* bnhg  = (const float*)d_in[16];
    const float* bnhb  = (const float*)d_in[17];
    float* out = (float*)d_out;

    char* ws = (char*)d_ws;
    unsigned char* modeq = (unsigned char*)ws;             // 3,145,728 B
    float* tpart  = (float*)(ws + 3145728);                // 32*64 f = 8,192 B
    float* pstats = (float*)(ws + 3145728 + 8192);         // 128*12 f = 6,144 B
    float* p1 = (float*)(ws + 3160064);                    // 64 f
    float* p2 = p1 + 64;                                   // 64 f
    float* lp = p2 + 64;                                   // 768 f (ends 3,163,968; pad to 3,164,160)
    unsigned* partial = (unsigned*)(ws + 3164160);         // 128*4913 u32 = 2,515,456 B
    float* d1 = (float*)(ws + 3164160 + 2515456);          // 3,742,848 f
    float* d2 = d1 + 3742848;                              // 415,872 f
    float* d3 = d2 + 415872;                               // 46,208 f
    float* d4 = d3 + 46208;                                // 6,272 f
    float* d5 = d4 + 6272;                                 // 1,152 f
    float* d6 = d5 + 1152;                                 // 128 f

    mode_kernel<<<dim3(2, 32, 12), 256, 0, stream>>>(x, modeq);
    hist_kernel<<<128, 256, 0, stream>>>(modeq, partial);
    solveBF_kernel<<<32, 256, 0, stream>>>(partial, w1, b1, w2, b2,
                                           bn1g, bn1b, p1, tpart);
    fin2_kernel<<<1, 32, 0, stream>>>(tpart, w3, b3, bn2g, bn2b, p2);
    d1_kernel<<<dim3(3, 171, 4), 64, 0, stream>>>(modeq, w1, b1, w2, b2, w3, b3,
                                                  p1, p2, kd, d1);
    pyramid_kernel<<<128, 256, 0, stream>>>(d1, d2, d3, d4, d5, d6, kd, pstats);
    fin3_kernel<<<1, 192, 0, stream>>>(pstats, kw, bnwg, bnwb, kh, bnhg, bnhb, lp);
    final_kernel<<<32768, 256, 0, stream>>>(d1, d2, d3, d4, d5, d6, lp, out);
}

// Round 10
// 468.500 us; speedup vs baseline: 1.1284x; 1.1284x over previous
//
#include <hip/hip_runtime.h>

#define HH 512
#define WW 512
#define HW 262144          // 512*512
#define NPIX 1048576       // 4*512*512
#define NPIXF 1048576.0f

typedef float f4 __attribute__((ext_vector_type(4)));

__device__ __forceinline__ float leaky(float v) { return v > 0.f ? v : 0.01f * v; }

// replication count of source index i at level size s (nearest upsample to 512)
__device__ __forceinline__ float repw(int i, int s) {
    return (float)(((i + 1) * 512 + s - 1) / s - (i * 512 + s - 1) / s);
}

__device__ __forceinline__ void hins(unsigned long long& h0, unsigned long long& h1,
                                     unsigned& c16, int val) {
    unsigned long long inc = 1ull << ((val & 7) * 8);
    h0 += (val < 8) ? inc : 0;
    h1 += (val >= 8 && val < 16) ? inc : 0;
    c16 += (unsigned)(val >> 4);
}
__device__ __forceinline__ void hrem(unsigned long long& h0, unsigned long long& h1,
                                     unsigned& c16, int val) {
    unsigned long long inc = 1ull << ((val & 7) * 8);
    h0 -= (val < 8) ? inc : 0;
    h1 -= (val >= 8 && val < 16) ? inc : 0;
    c16 -= (unsigned)(val >> 4);
}

// ---------------------------------------------------------------------------
// Mode pooling v3 (round-5 proven): 768 blocks, 16 rows x 256 cols,
// double-buffered colhist mirror, one __syncthreads per row.
// ---------------------------------------------------------------------------
__global__ __launch_bounds__(256) void mode_kernel(const float* __restrict__ x,
                                                   unsigned char* __restrict__ modeq) {
    __shared__ unsigned char q[26 * 272];
    __shared__ unsigned ch[2][267 * 5];
    const int plane = blockIdx.z;
    const int tc0 = blockIdx.x * 256;
    const int tr0 = blockIdx.y * 16;
    const float* xp = x + (size_t)plane * HW;
    for (int idx = threadIdx.x; idx < 26 * 266; idx += 256) {
        int r = idx / 266;
        int cc = idx - r * 266;
        int gr = tr0 + r - 5; gr = gr < 0 ? -gr : (gr > 511 ? 1022 - gr : gr);
        int gc = tc0 + cc - 5; gc = gc < 0 ? -gc : (gc > 511 ? 1022 - gc : gc);
        float v = rintf(xp[gr * WW + gc] * 15.9375f);   // 255/16, round-half-even
        v = fminf(fmaxf(v, 0.f), 16.f);
        q[r * 272 + cc] = (unsigned char)(int)v;
    }
    const int t = threadIdx.x;
    unsigned long long A0 = 0, A1 = 0; unsigned A2 = 0;
    unsigned long long B0 = 0, B1 = 0; unsigned B2 = 0;
    __syncthreads();
    for (int r = 0; r < 16; ++r) {
        if (r == 0) {
            #pragma unroll
            for (int v = 0; v < 11; ++v) {
                hins(A0, A1, A2, q[v * 272 + t]);
                if (t < 10) hins(B0, B1, B2, q[v * 272 + 256 + t]);
            }
        } else {
            hrem(A0, A1, A2, q[(r - 1) * 272 + t]);
            hins(A0, A1, A2, q[(r + 10) * 272 + t]);
            if (t < 10) {
                hrem(B0, B1, B2, q[(r - 1) * 272 + 256 + t]);
                hins(B0, B1, B2, q[(r + 10) * 272 + 256 + t]);
            }
        }
        unsigned* cb = ch[r & 1];
        cb[t * 5 + 0] = (unsigned)A0;
        cb[t * 5 + 1] = (unsigned)(A0 >> 32);
        cb[t * 5 + 2] = (unsigned)A1;
        cb[t * 5 + 3] = (unsigned)(A1 >> 32);
        cb[t * 5 + 4] = A2;
        if (t < 10) {
            cb[(256 + t) * 5 + 0] = (unsigned)B0;
            cb[(256 + t) * 5 + 1] = (unsigned)(B0 >> 32);
            cb[(256 + t) * 5 + 2] = (unsigned)B1;
            cb[(256 + t) * 5 + 3] = (unsigned)(B1 >> 32);
            cb[(256 + t) * 5 + 4] = B2;
        }
        __syncthreads();
        unsigned long long H0 = 0, H1 = 0; unsigned C = 0;
        #pragma unroll
        for (int v = 0; v < 11; ++v) {
            const unsigned* p = &cb[(t + v) * 5];
            H0 += (unsigned long long)p[0] | ((unsigned long long)p[1] << 32);
            H1 += (unsigned long long)p[2] | ((unsigned long long)p[3] << 32);
            C += p[4];
        }
        unsigned m = 0;
        #pragma unroll
        for (int i = 0; i < 8; ++i) {
            unsigned cnt = (unsigned)(H0 >> (8 * i)) & 0xFFu;
            unsigned val = (cnt << 8) | (unsigned)(16 - i);
            m = m > val ? m : val;
        }
        #pragma unroll
        for (int i = 8; i < 16; ++i) {
            unsigned cnt = (unsigned)(H1 >> (8 * (i - 8))) & 0xFFu;
            unsigned val = (cnt << 8) | (unsigned)(16 - i);
            m = m > val ? m : val;
        }
        unsigned val16 = (C << 8);
        m = m > val16 ? m : val16;
        int k = 16 - (int)(m & 0xFFu);
        modeq[(size_t)plane * HW + (size_t)(tr0 + r) * WW + tc0 + t] = (unsigned char)k;
    }
}

// ---------------------------------------------------------------------------
// Joint histogram + per-block t1 moments (non-atomic mpart). 128 blocks,
// coalesced partial[blk*4913+bin] writes. (Round-6/7 validated pattern.)
// ---------------------------------------------------------------------------
__global__ __launch_bounds__(256) void hist_kernel(const unsigned char* __restrict__ modeq,
                                                   const float* __restrict__ w1,
                                                   const float* __restrict__ b1,
                                                   unsigned* __restrict__ partial,
                                                   float* __restrict__ mpart) {
    __shared__ unsigned lh[4913];
    __shared__ float mred[27][4];
    for (int i = threadIdx.x; i < 4913; i += 256) lh[i] = 0;
    __syncthreads();
    int base = blockIdx.x * 8192;
    int b = base >> 18;
    int hw0 = base & (HW - 1);
    const unsigned char* mp = modeq + (size_t)b * 3 * HW;
    #pragma unroll
    for (int j = 0; j < 8; ++j) {
        int g = threadIdx.x + 256 * j;
        int hw = hw0 + g * 4;
        unsigned u0 = *(const unsigned*)(mp + hw);
        unsigned u1 = *(const unsigned*)(mp + hw + HW);
        unsigned u2 = *(const unsigned*)(mp + hw + 2 * HW);
        #pragma unroll
        for (int k = 0; k < 4; ++k) {
            int k0 = (u0 >> (8 * k)) & 0xFF;
            int k1 = (u1 >> (8 * k)) & 0xFF;
            int k2 = (u2 >> (8 * k)) & 0xFF;
            atomicAdd(&lh[k0 + 17 * k1 + 289 * k2], 1u);
        }
    }
    __syncthreads();
    unsigned* pp = partial + blockIdx.x * 4913;
    for (int i = threadIdx.x; i < 4913; i += 256) pp[i] = lh[i];
    float w1r[18], b1r[6];
    #pragma unroll
    for (int k = 0; k < 18; ++k) w1r[k] = w1[k];
    #pragma unroll
    for (int o = 0; o < 6; ++o) b1r[o] = b1[o];
    float M[27];
    #pragma unroll
    for (int i = 0; i < 27; ++i) M[i] = 0.f;
    for (int bin = threadIdx.x; bin < 4913; bin += 256) {
        float cnt = (float)lh[bin];
        int k0 = bin % 17;
        int r = bin / 17;
        int k1 = r % 17;
        int k2 = r / 17;
        float xm0 = k0 * 0.0625f, xm1 = k1 * 0.0625f, xm2 = k2 * 0.0625f;
        float t1[6];
        #pragma unroll
        for (int o = 0; o < 6; ++o)
            t1[o] = leaky(xm0 * w1r[o * 3] + xm1 * w1r[o * 3 + 1] + xm2 * w1r[o * 3 + 2] + b1r[o]);
        #pragma unroll
        for (int o = 0; o < 6; ++o) M[o] += cnt * t1[o];
        int ii = 6;
        #pragma unroll
        for (int j = 0; j < 6; ++j)
            #pragma unroll
            for (int k = j; k < 6; ++k) { M[ii] += cnt * t1[j] * t1[k]; ++ii; }
    }
    int wv = threadIdx.x >> 6;
    #pragma unroll
    for (int i = 0; i < 27; ++i) {
        float v = M[i];
        #pragma unroll
        for (int off = 32; off >= 1; off >>= 1) v += __shfl_xor(v, off);
        if ((threadIdx.x & 63) == 0) mred[i][wv] = v;
    }
    __syncthreads();
    if (threadIdx.x < 27)
        mpart[blockIdx.x * 27 + threadIdx.x] =
            mred[threadIdx.x][0] + mred[threadIdx.x][1] +
            mred[threadIdx.x][2] + mred[threadIdx.x][3];
}

// Round-5 proven redhist: ONE pass, 1 bin/thread, 128 loads/thread, coalesced.
__global__ __launch_bounds__(256) void redhist_kernel(const unsigned* __restrict__ partial,
                                                      float* __restrict__ histf) {
    int bin = blockIdx.x * 256 + threadIdx.x;
    if (bin >= 4913) return;
    unsigned s = 0;
    for (int blk = 0; blk < 128; ++blk) s += partial[blk * 4913 + bin];
    histf[bin] = (float)s;
}

// BN1 closed form from mpart -> p1. 1 block.
__global__ void solveA_kernel(const float* __restrict__ mpart, const float* __restrict__ w2,
                              const float* __restrict__ b2, const float* __restrict__ g1,
                              const float* __restrict__ bb1, float* __restrict__ p1) {
    __shared__ float mom[27];
    int t = threadIdx.x;
    if (t < 27) {
        float s = 0.f;
        for (int blk = 0; blk < 128; ++blk) s += mpart[blk * 27 + t];
        mom[t] = s;
    }
    __syncthreads();
    if (t < 32) {
        float w2r[6];
        #pragma unroll
        for (int k = 0; k < 6; ++k) w2r[k] = w2[t * 6 + k];
        float b2c = b2[t];
        float wm1 = 0.f;
        #pragma unroll
        for (int k = 0; k < 6; ++k) wm1 += w2r[k] * mom[k];
        float q = 0.f;
        int ii = 6;
        #pragma unroll
        for (int j = 0; j < 6; ++j)
            #pragma unroll
            for (int k = j; k < 6; ++k) {
                float f = w2r[j] * w2r[k] * mom[ii];
                q += (j == k) ? f : 2.f * f;
                ++ii;
            }
        float mean = b2c + wm1 / NPIXF;
        float ex2 = b2c * b2c + 2.f * b2c * (wm1 / NPIXF) + q / NPIXF;
        float var = ex2 - mean * mean;
        float a = g1[t] * rsqrtf(var + 1e-5f);
        p1[t] = a;
        p1[32 + t] = bb1[t] - mean * a;
    }
}

// t = leaky(bn1(h2)) stats via bin sweep over reduced histf (broadcast reads),
// 32 blocks, non-atomic tpart. (Round-5 proven shape minus atomics.)
__global__ __launch_bounds__(256) void solveB_kernel(const float* __restrict__ histf,
                                                     const float* __restrict__ w1,
                                                     const float* __restrict__ b1,
                                                     const float* __restrict__ w2,
                                                     const float* __restrict__ b2,
                                                     const float* __restrict__ p1,
                                                     float* __restrict__ tpart) {
    __shared__ float rs[8][32], rq[8][32];
    int c = threadIdx.x & 31;
    int sub = threadIdx.x >> 5;
    float w1r[18], b1r[6];
    #pragma unroll
    for (int k = 0; k < 18; ++k) w1r[k] = w1[k];
    #pragma unroll
    for (int o = 0; o < 6; ++o) b1r[o] = b1[o];
    float w2r[6];
    #pragma unroll
    for (int k = 0; k < 6; ++k) w2r[k] = w2[c * 6 + k];
    float b2c = b2[c];
    float a1 = p1[c], c1 = p1[32 + c];
    float sm = 0.f, sq = 0.f;
    for (int bin = blockIdx.x + 32 * sub; bin < 4913; bin += 256) {
        float cnt = histf[bin];
        int k0 = bin % 17;
        int r = bin / 17;
        int k1 = r % 17;
        int k2 = r / 17;
        float xm0 = k0 * 0.0625f, xm1 = k1 * 0.0625f, xm2 = k2 * 0.0625f;
        float t1[6];
        #pragma unroll
        for (int o = 0; o < 6; ++o)
            t1[o] = leaky(xm0 * w1r[o * 3] + xm1 * w1r[o * 3 + 1] + xm2 * w1r[o * 3 + 2] + b1r[o]);
        float h2 = b2c;
        #pragma unroll
        for (int k = 0; k < 6; ++k) h2 += w2r[k] * t1[k];
        float tt = leaky(a1 * h2 + c1);
        sm += cnt * tt;
        sq += cnt * tt * tt;
    }
    rs[sub][c] = sm; rq[sub][c] = sq;
    __syncthreads();
    if (threadIdx.x < 32) {
        float s = 0.f, qq = 0.f;
        #pragma unroll
        for (int g = 0; g < 8; ++g) { s += rs[g][threadIdx.x]; qq += rq[g][threadIdx.x]; }
        tpart[blockIdx.x * 64 + threadIdx.x] = s;
        tpart[blockIdx.x * 64 + 32 + threadIdx.x] = qq;
    }
}

__global__ void fin2_kernel(const float* __restrict__ tpart, const float* __restrict__ w3,
                            const float* __restrict__ b3, const float* __restrict__ g,
                            const float* __restrict__ bb, float* __restrict__ p2) {
    int c = threadIdx.x;
    float s = 0.f, qq = 0.f;
    #pragma unroll
    for (int k = 0; k < 32; ++k) { s += tpart[k * 64 + c]; qq += tpart[k * 64 + 32 + c]; }
    float mt = s / NPIXF;
    float vt = qq / NPIXF - mt * mt;
    float m2 = w3[c] * mt + b3[c];
    float v2 = w3[c] * w3[c] * vt;
    float a = g[c] * rsqrtf(v2 + 1e-5f);
    p2[c] = a;
    p2[32 + c] = bb[c] - m2 * a;
}

// ---------------------------------------------------------------------------
// Level-1 downsample fused with prepare chain (round-5 proven).
// ---------------------------------------------------------------------------
__global__ __launch_bounds__(64) void d1_kernel(const unsigned char* __restrict__ modeq,
                                                const float* __restrict__ w1,
                                                const float* __restrict__ b1,
                                                const float* __restrict__ w2,
                                                const float* __restrict__ b2,
                                                const float* __restrict__ w3,
                                                const float* __restrict__ b3,
                                                const float* __restrict__ p1,
                                                const float* __restrict__ p2,
                                                const float* __restrict__ kd,
                                                float* __restrict__ d1) {
    int j = blockIdx.x * 64 + threadIdx.x;
    if (j >= 171) return;
    int i = blockIdx.y;
    int b = blockIdx.z;
    float acc[32];
    #pragma unroll
    for (int c = 0; c < 32; ++c) acc[c] = 0.f;
    const unsigned char* mp = modeq + (size_t)b * 3 * HW;
    #pragma unroll
    for (int u = 0; u < 3; ++u) {
        int r = 3 * i - 1 + u;
        if (r < 0 || r > 511) continue;
        #pragma unroll
        for (int v = 0; v < 3; ++v) {
            int col = 3 * j - 1 + v;
            if (col < 0 || col > 511) continue;
            int off = r * WW + col;
            float xm0 = mp[off] * 0.0625f, xm1 = mp[off + HW] * 0.0625f, xm2 = mp[off + 2 * HW] * 0.0625f;
            float t1[6];
            #pragma unroll
            for (int o = 0; o < 6; ++o)
                t1[o] = leaky(xm0 * w1[o * 3] + xm1 * w1[o * 3 + 1] + xm2 * w1[o * 3 + 2] + b1[o]);
            #pragma unroll
            for (int c = 0; c < 32; ++c) {
                float h2 = b2[c];
                #pragma unroll
                for (int k = 0; k < 6; ++k) h2 += w2[c * 6 + k] * t1[k];
                float t = leaky(h2 * p1[c] + p1[32 + c]);
                float uu = t * w3[c] + b3[c];
                float hv = leaky(uu * p2[c] + p2[32 + c]);
                acc[c] += hv * kd[c * 9 + u * 3 + v];
            }
        }
    }
    size_t base = ((size_t)(b * 32) * 171 + i) * 171 + j;
    #pragma unroll
    for (int c = 0; c < 32; ++c) d1[base + (size_t)c * 29241] = acc[c];
}

// ---------------------------------------------------------------------------
// Fused pyramid tail: L1 stats + levels 2..6 + stats, pstats non-atomic.
// ---------------------------------------------------------------------------
__device__ __forceinline__ void red_store(float sm, float sq, float* rsc, float* ps) {
    #pragma unroll
    for (int off = 32; off >= 1; off >>= 1) {
        sm += __shfl_xor(sm, off);
        sq += __shfl_xor(sq, off);
    }
    __syncthreads();
    int wv = threadIdx.x >> 6;
    if ((threadIdx.x & 63) == 0) { rsc[wv] = sm; rsc[8 + wv] = sq; }
    __syncthreads();
    if (threadIdx.x == 0) {
        ps[0] = rsc[0] + rsc[1] + rsc[2] + rsc[3];
        ps[1] = rsc[8] + rsc[9] + rsc[10] + rsc[11];
    }
}

__device__ __forceinline__ void lvl(const float* src, int sin, float* dstL,
                                    float* dstG, int sout, const float* kreg,
                                    float* rsc, float* ps) {
    float sm = 0.f, sq = 0.f;
    int n = sout * sout;
    for (int i = threadIdx.x; i < n; i += 256) {
        int oi = i / sout, oj = i - oi * sout;
        float acc = 0.f;
        #pragma unroll
        for (int u = 0; u < 3; ++u) {
            int r = 3 * oi - 1 + u;
            if ((unsigned)r >= (unsigned)sin) continue;
            #pragma unroll
            for (int v = 0; v < 3; ++v) {
                int cc = 3 * oj - 1 + v;
                if ((unsigned)cc >= (unsigned)sin) continue;
                acc += src[r * sin + cc] * kreg[u * 3 + v];
            }
        }
        dstG[i] = acc;
        if (dstL) dstL[i] = acc;
        float w = repw(oi, sout) * repw(oj, sout);
        sm += w * acc;
        sq += w * acc * acc;
    }
    red_store(sm, sq, rsc, ps);
}

__global__ __launch_bounds__(256) void pyramid_kernel(const float* __restrict__ d1,
                                                      float* __restrict__ d2,
                                                      float* __restrict__ d3,
                                                      float* __restrict__ d4,
                                                      float* __restrict__ d5,
                                                      float* __restrict__ d6,
                                                      const float* __restrict__ kd,
                                                      float* __restrict__ pstats) {
    __shared__ float buf2[3249];
    __shared__ float buf3[361];
    __shared__ float buf4[49];
    __shared__ float buf5[9];
    __shared__ float rsc[16];
    int bc = blockIdx.x;
    int c = bc & 31;
    float kreg[9];
    #pragma unroll
    for (int qq = 0; qq < 9; ++qq) kreg[qq] = kd[c * 9 + qq];
    float* ps = pstats + (size_t)bc * 12;
    const float* s1 = d1 + (size_t)bc * 29241;
    float sm = 0.f, sq = 0.f;
    for (int i = threadIdx.x; i < 29241; i += 256) {
        int oi = i / 171, oj = i - oi * 171;
        float w = repw(oi, 171) * repw(oj, 171);
        float v = s1[i];
        sm += w * v;
        sq += w * v * v;
    }
    red_store(sm, sq, rsc, ps + 0);
    lvl(s1, 171, buf2, d2 + (size_t)bc * 3249, 57, kreg, rsc, ps + 2);
    lvl(buf2, 57, buf3, d3 + (size_t)bc * 361, 19, kreg, rsc, ps + 4);
    lvl(buf3, 19, buf4, d4 + (size_t)bc * 49, 7, kreg, rsc, ps + 6);
    lvl(buf4, 7, buf5, d5 + (size_t)bc * 9, 3, kreg, rsc, ps + 8);
    lvl(buf5, 3, nullptr, d6 + bc, 1, kreg, rsc, ps + 10);
}

// Separate fin3 (round-5 proven shape), reading non-atomic pstats.
__global__ void fin3_kernel(const float* __restrict__ pstats, const float* __restrict__ kw,
                            const float* __restrict__ gw, const float* __restrict__ bw,
                            const float* __restrict__ kh, const float* __restrict__ gh,
                            const float* __restrict__ bh, float* __restrict__ lp) {
    int t = threadIdx.x;
    if (t >= 192) return;
    int l = t >> 5, c = t & 31;
    float sm = 0.f, sq = 0.f;
    #pragma unroll
    for (int b = 0; b < 4; ++b) {
        const float* ps = pstats + (size_t)(b * 32 + c) * 12 + 2 * l;
        sm += ps[0];
        sq += ps[1];
    }
    float mz = sm / NPIXF;
    float vz = sq / NPIXF - mz * mz;
    float kwc = kw[c];
    float aw = gw[c] * rsqrtf(kwc * kwc * vz + 1e-5f);
    float khc = kh[c];
    float ah = gh[c] * rsqrtf(khc * khc * vz + 1e-5f);
    float* o = lp + (size_t)(l * 32 + c) * 4;
    o[0] = kwc * aw;
    o[1] = bw[c] - kwc * mz * aw;
    o[2] = khc * ah;
    o[3] = bh[c] - khc * mz * ah;
}

// Final (round-5 proven): 4 px/thread, nontemporal float4 stores, reads lp.
__global__ __launch_bounds__(256) void final_kernel(const float* __restrict__ d1,
                                                    const float* __restrict__ d2,
                                                    const float* __restrict__ d3,
                                                    const float* __restrict__ d4,
                                                    const float* __restrict__ d5,
                                                    const float* __restrict__ d6,
                                                    const float* __restrict__ lp,
                                                    float* __restrict__ out) {
    int idx = blockIdx.x * 256 + threadIdx.x;
    int w4 = (idx & 127) << 2;
    int h = (idx >> 7) & 511;
    int c = (idx >> 16) & 31;
    int b = idx >> 21;
    const float* ds[6] = {d1, d2, d3, d4, d5, d6};
    const int ss[6] = {171, 57, 19, 7, 3, 1};
    float accw[4] = {0.f, 0.f, 0.f, 0.f};
    float acch[4] = {0.f, 0.f, 0.f, 0.f};
    #pragma unroll
    for (int l = 0; l < 6; ++l) {
        int s = ss[l];
        int sh = (h * s) >> 9;
        const float* base = ds[l] + ((size_t)(b * 32 + c) * s + sh) * s;
        const float* a = lp + (size_t)(l * 32 + c) * 4;
        float a0 = a[0], a1 = a[1], a2 = a[2], a3 = a[3];
        #pragma unroll
        for (int k = 0; k < 4; ++k) {
            int sw = ((w4 + k) * s) >> 9;
            float val = base[sw];
            accw[k] += leaky(val * a0 + a1);
            acch[k] += leaky(val * a2 + a3);
        }
    }
    size_t o = (((size_t)(b * 64 + c)) << 18) + ((size_t)h << 9) + w4;
    f4 vw = {accw[0], accw[1], accw[2], accw[3]};
    f4 vh = {acch[0], acch[1], acch[2], acch[3]};
    __builtin_nontemporal_store(vw, (f4*)(out + o));
    __builtin_nontemporal_store(vh, (f4*)(out + o + (((size_t)32) << 18)));
}

extern "C" void kernel_launch(void* const* d_in, const int* in_sizes, int n_in,
                              void* d_out, int out_size, void* d_ws, size_t ws_size,
                              hipStream_t stream) {
    const float* x     = (const float*)d_in[0];
    const float* w1    = (const float*)d_in[1];
    const float* b1    = (const float*)d_in[2];
    const float* w2    = (const float*)d_in[3];
    const float* b2    = (const float*)d_in[4];
    const float* bn1g  = (const float*)d_in[5];
    const float* bn1b  = (const float*)d_in[6];
    const float* w3    = (const float*)d_in[7];
    const float* b3    = (const float*)d_in[8];
    const float* bn2g  = (const float*)d_in[9];
    const float* bn2b  = (const float*)d_in[10];
    const float* kd    = (const float*)d_in[11];
    const float* kw    = (const float*)d_in[12];
    const float* bnwg  = (const float*)d_in[13];
    const float* bnwb  = (const float*)d_in[14];
    const float* kh    = (const float*)d_in[15];
    const float* bnhg  = (const float*)d_in[16];
    const float* bnhb  = (const float*)d_in[17];
    float* out = (float*)d_out;

    char* ws = (char*)d_ws;
    unsigned char* modeq = (unsigned char*)ws;             // 3,145,728 B
    float* mpart  = (float*)(ws + 3145728);                // 128*27 f = 13,824 B
    float* tpart  = (float*)(ws + 3145728 + 13824);        // 32*64 f = 8,192 B
    float* pstats = (float*)(ws + 3145728 + 13824 + 8192); // 128*12 f = 6,144 B
    float* p1 = (float*)(ws + 3174400);                    // 64 f
    float* p2 = p1 + 64;                                   // 64 f
    float* lp = p2 + 64;                                   // 768 f (ends 3,178,240; pad)
    float* histf = (float*)(ws + 3178496);                 // 4913 f (pad to 20,480 B)
    unsigned* partial = (unsigned*)(ws + 3178496 + 20480); // 128*4913 u32 = 2,515,456 B
    float* d1 = (float*)(ws + 3198976 + 2515456);          // 3,742,848 f
    float* d2 = d1 + 3742848;                              // 415,872 f
    float* d3 = d2 + 415872;                               // 46,208 f
    float* d4 = d3 + 46208;                                // 6,272 f
    float* d5 = d4 + 6272;                                 // 1,152 f
    float* d6 = d5 + 1152;                                 // 128 f

    mode_kernel<<<dim3(2, 32, 12), 256, 0, stream>>>(x, modeq);
    hist_kernel<<<128, 256, 0, stream>>>(modeq, w1, b1, partial, mpart);
    redhist_kernel<<<20, 256, 0, stream>>>(partial, histf);
    solveA_kernel<<<1, 32, 0, stream>>>(mpart, w2, b2, bn1g, bn1b, p1);
    solveB_kernel<<<32, 256, 0, stream>>>(histf, w1, b1, w2, b2, p1, tpart);
    fin2_kernel<<<1, 32, 0, stream>>>(tpart, w3, b3, bn2g, bn2b, p2);
    d1_kernel<<<dim3(3, 171, 4), 64, 0, stream>>>(modeq, w1, b1, w2, b2, w3, b3,
                                                  p1, p2, kd, d1);
    pyramid_kernel<<<128, 256, 0, stream>>>(d1, d2, d3, d4, d5, d6, kd, pstats);
    fin3_kernel<<<1, 192, 0, stream>>>(pstats, kw, bnwg, bnwb, kh, bnhg, bnhb, lp);
    final_kernel<<<32768, 256, 0, stream>>>(d1, d2, d3, d4, d5, d6, lp, out);
}